// Round 2
// baseline (3355.418 us; speedup 1.0000x reference)
//
#include <hip/hip_runtime.h>

// Problem: LSTM-like scan. x:[B,T] f32, W:[H+1,H] f32, b:[H] f32 -> out:[B,T,H] f32.
// B=256, T=2048, H=128.
// g_j = sum_i h_i*W[i,j] + x_t*W[H,j] + b_j ; sg = sigmoid(g);
// c = sg*(c+g); h = sg*c; out[b,t,:] = h.
//
// Design: one block per batch row (recurrences independent across B).
// Thread j owns output column j; W[:,j] lives in 128 VGPRs; h is double-buffered
// in LDS (one barrier per step); x row staged in LDS up front.

#define BB 256
#define TT 2048
#define HH 128

__global__ __launch_bounds__(HH, 1) void lstm_scan_kernel(
    const float* __restrict__ x,   // [B, T]
    const float* __restrict__ W,   // [H+1, H]
    const float* __restrict__ b,   // [H]
    float* __restrict__ out)       // [B, T, H]
{
    const int j = threadIdx.x;       // 0..127 : output column
    const int batch = blockIdx.x;    // 0..255

    __shared__ float xs[TT];         // 8 KB : this batch row's x
    __shared__ float hbuf[2][HH];    // 1 KB : double-buffered hidden state

    // Stage x[batch, :] into LDS (coalesced).
    for (int t = j; t < TT; t += HH) {
        xs[t] = x[(size_t)batch * TT + t];
    }
    hbuf[0][j] = 0.0f;

    // Load W column j into registers (one-time; coalesced across threads per row).
    float wcol[HH];
#pragma unroll
    for (int i = 0; i < HH; ++i) {
        wcol[i] = W[i * HH + j];
    }
    const float wx   = W[HH * HH + j];
    const float bias = b[j];

    float c = 0.0f;
    float* outp = out + (size_t)batch * TT * HH + j;

    __syncthreads();

    for (int t = 0; t < TT; ++t) {
        const int cur = t & 1;
        const float xt = xs[t];
        const float4* hv = (const float4*)(hbuf[cur]);

        // g = bias + xt*wx + sum_i h[i] * W[i][j]
        float a0 = fmaf(xt, wx, bias);
        float a1 = 0.0f, a2 = 0.0f, a3 = 0.0f;
#pragma unroll
        for (int i = 0; i < HH / 4; ++i) {
            const float4 v = hv[i];   // broadcast LDS read (conflict-free)
            a0 = fmaf(v.x, wcol[4 * i + 0], a0);
            a1 = fmaf(v.y, wcol[4 * i + 1], a1);
            a2 = fmaf(v.z, wcol[4 * i + 2], a2);
            a3 = fmaf(v.w, wcol[4 * i + 3], a3);
        }
        const float g = (a0 + a1) + (a2 + a3);
        const float sg = 1.0f / (1.0f + __expf(-g));
        c = sg * (c + g);
        const float hn = sg * c;

        hbuf[cur ^ 1][j] = hn;            // write next-step buffer
        outp[(size_t)t * HH] = hn;        // fire-and-forget store
        __syncthreads();                  // single barrier per step
    }
}

extern "C" void kernel_launch(void* const* d_in, const int* in_sizes, int n_in,
                              void* d_out, int out_size, void* d_ws, size_t ws_size,
                              hipStream_t stream) {
    const float* x = (const float*)d_in[0];
    const float* W = (const float*)d_in[1];
    const float* b = (const float*)d_in[2];
    float* out = (float*)d_out;

    lstm_scan_kernel<<<BB, HH, 0, stream>>>(x, W, b, out);
}

// Round 3
// 1445.782 us; speedup vs baseline: 2.3208x; 2.3208x over previous
//
#include <hip/hip_runtime.h>

// LSTM-like scan. x:[B,T] f32, W:[H+1,H] f32, b:[H] f32 -> out:[B,T,H] f32.
// B=256, T=2048, H=128.
// g_j = sum_i h_i*W[i,j] + x_t*W[H,j] + b_j ; sg = sigmoid(g);
// c = sg*(c+g); h = sg*c; out[b,t,:] = h.
//
// One block (128 thr = 2 waves) per batch row; 256 blocks = 1/CU.
// Thread j owns column j. W[:,j] pinned in 32 NAMED float4 VGPRs (round 2
// showed an indexable array gets demoted to scratch -> 3750 cyc/step).
// h double-buffered in LDS; inter-wave sync via raw s_barrier with only
// lgkmcnt(0) so per-step output stores are NOT drained in the serial chain.

#define BB 256
#define TT 2048
#define HH 128

#define LOADW(k) \
    float4 w##k = make_float4(W[(4*(k)+0)*HH + j], W[(4*(k)+1)*HH + j], \
                              W[(4*(k)+2)*HH + j], W[(4*(k)+3)*HH + j]);

#define FMASTEP(k) { \
    const float4 hv = hs4[(k)]; \
    a0 = fmaf(hv.x, w##k.x, a0); \
    a1 = fmaf(hv.y, w##k.y, a1); \
    a2 = fmaf(hv.z, w##k.z, a2); \
    a3 = fmaf(hv.w, w##k.w, a3); }

__global__ __launch_bounds__(HH, 1) void lstm_scan_kernel(
    const float* __restrict__ x,   // [B, T]
    const float* __restrict__ W,   // [H+1, H]
    const float* __restrict__ b,   // [H]
    float* __restrict__ out)       // [B, T, H]
{
    const int j = threadIdx.x;       // 0..127 : output column
    const int batch = blockIdx.x;    // 0..255

    __shared__ float xs[TT];         // 8 KB : this batch row's x
    __shared__ float hbuf[2][HH];    // 1 KB : double-buffered hidden state

    for (int t = j; t < TT; t += HH) {
        xs[t] = x[(size_t)batch * TT + t];
    }
    hbuf[0][j] = 0.0f;

    // W column j -> 32 named float4s (must stay in VGPRs).
    LOADW(0)  LOADW(1)  LOADW(2)  LOADW(3)  LOADW(4)  LOADW(5)  LOADW(6)  LOADW(7)
    LOADW(8)  LOADW(9)  LOADW(10) LOADW(11) LOADW(12) LOADW(13) LOADW(14) LOADW(15)
    LOADW(16) LOADW(17) LOADW(18) LOADW(19) LOADW(20) LOADW(21) LOADW(22) LOADW(23)
    LOADW(24) LOADW(25) LOADW(26) LOADW(27) LOADW(28) LOADW(29) LOADW(30) LOADW(31)
    const float wx   = W[HH * HH + j];
    const float bias = b[j];

    float c = 0.0f;
    float* outp = out + (size_t)batch * TT * HH + j;

    __syncthreads();   // one-time: covers x staging + h init

    for (int t = 0; t < TT; ++t) {
        const int cur = t & 1;
        const float xt = xs[t];
        const float4* hs4 = (const float4*)(hbuf[cur]);

        float a0 = fmaf(xt, wx, bias);
        float a1 = 0.0f, a2 = 0.0f, a3 = 0.0f;
        FMASTEP(0)  FMASTEP(1)  FMASTEP(2)  FMASTEP(3)
        FMASTEP(4)  FMASTEP(5)  FMASTEP(6)  FMASTEP(7)
        FMASTEP(8)  FMASTEP(9)  FMASTEP(10) FMASTEP(11)
        FMASTEP(12) FMASTEP(13) FMASTEP(14) FMASTEP(15)
        FMASTEP(16) FMASTEP(17) FMASTEP(18) FMASTEP(19)
        FMASTEP(20) FMASTEP(21) FMASTEP(22) FMASTEP(23)
        FMASTEP(24) FMASTEP(25) FMASTEP(26) FMASTEP(27)
        FMASTEP(28) FMASTEP(29) FMASTEP(30) FMASTEP(31)

        const float g = (a0 + a1) + (a2 + a3);
        const float sg = 1.0f / (1.0f + __expf(-g));
        c = sg * (c + g);
        const float hn = sg * c;

        hbuf[cur ^ 1][j] = hn;       // next-step buffer
        outp[(size_t)t * HH] = hn;   // fire-and-forget (never drained below)

        // LDS-only sync: wait our ds ops, barrier. Global stores stay in
        // flight (plain __syncthreads would force vmcnt(0) each step).
        asm volatile("s_waitcnt lgkmcnt(0)\n\ts_barrier" ::: "memory");
    }
}

extern "C" void kernel_launch(void* const* d_in, const int* in_sizes, int n_in,
                              void* d_out, int out_size, void* d_ws, size_t ws_size,
                              hipStream_t stream) {
    const float* x = (const float*)d_in[0];
    const float* W = (const float*)d_in[1];
    const float* b = (const float*)d_in[2];
    float* out = (float*)d_out;

    lstm_scan_kernel<<<BB, HH, 0, stream>>>(x, W, b, out);
}